// Round 4
// baseline (2596.279 us; speedup 1.0000x reference)
//
#include <hip/hip_runtime.h>
#include <hip/hip_bf16.h>
#include <math.h>

// Problem constants
#define NN 116           // nodes
#define NE 1160          // edges
#define CCH 256          // channels after conv
#define FF 653           // feature dim
#define KP 672           // padded feature stride (bf16), mult of 32
#define MM (NN*CCH)      // 29696 GEMM rows (= 232 * 128)
#define NPAD 768         // padded N for weight matrix (6 * 128)
#define SZH ((size_t)MM*KP)   // elems per bf16 h buffer

typedef unsigned short ushort;
typedef short bf16x8 __attribute__((ext_vector_type(8)));
typedef float f32x4 __attribute__((ext_vector_type(4)));

// ---- bf16 helpers (bit-level) ----------------------------------------------
__device__ __forceinline__ float bfbits_to_f(ushort u) {
    unsigned int w = ((unsigned int)u) << 16;
    return __uint_as_float(w);
}
__device__ __forceinline__ ushort f_to_bfbits(float f) {   // RTNE
    unsigned int u = __float_as_uint(f);
    u += 0x7FFFu + ((u >> 16) & 1u);
    return (ushort)(u >> 16);
}

__device__ __forceinline__ void gl_lds16(const void* g, void* l) {
    __builtin_amdgcn_global_load_lds(
        (const __attribute__((address_space(1))) unsigned int*)g,
        (__attribute__((address_space(3))) unsigned int*)l, 16, 0, 0);
}

// ---------------------------------------------------------------------------
// CSR build: per-dst incoming-edge source lists.
__global__ void build_csr_k(const int* __restrict__ ei, int* __restrict__ off,
                            int* __restrict__ lst) {
    __shared__ int s_cnt[NN];
    __shared__ int s_off[NN + 1];
    int t = threadIdx.x;
    for (int i = t; i < NN; i += blockDim.x) s_cnt[i] = 0;
    __syncthreads();
    for (int e = t; e < NE; e += blockDim.x) atomicAdd(&s_cnt[ei[NE + e]], 1);
    __syncthreads();
    if (t == 0) {
        s_off[0] = 0;
        for (int i = 0; i < NN; ++i) s_off[i + 1] = s_off[i] + s_cnt[i];
    }
    __syncthreads();
    for (int i = t; i < NN; i += blockDim.x) { off[i] = s_off[i]; s_cnt[i] = 0; }
    if (t == 0) off[NN] = s_off[NN];
    __syncthreads();
    for (int e = t; e < NE; e += blockDim.x) {
        int d = ei[NE + e];
        int p = atomicAdd(&s_cnt[d], 1);
        lst[s_off[d] + p] = ei[e];
    }
}

// ---------------------------------------------------------------------------
// Quantize + concat weights: Wc[2][NPAD][KP] bf16; pass0=Wl, pass1=Wr, zero pad.
__global__ void build_wc_k(const float* __restrict__ wl, const float* __restrict__ wr,
                           ushort* __restrict__ wc) {
    int idx = blockIdx.x * 256 + threadIdx.x;
    const int total = 2 * NPAD * KP;
    if (idx >= total) return;
    int k = idx % KP;
    int rem = idx / KP;
    int n = rem % NPAD;
    int p = rem / NPAD;
    float v = 0.f;
    if (n < FF && k < FF) v = (p ? wr : wl)[(size_t)n * FF + k];
    wc[idx] = f_to_bfbits(v);
}

// ---------------------------------------------------------------------------
// Grouped Conv1d -> bf16 h [MM][KP], zero pads.
// Block = (node n, group g). x window (16 in-ch x 657) staged in LDS once
// (contiguous copy). 512 threads: tid>>7 = out-ch quarter (16 ch), tid&127 = f
// lane; each thread walks f in steps of 128. Weights on scalar path (wave-
// uniform addresses). Computes all f unconditionally (padded LDS), masks store.
__global__ __launch_bounds__(512) void conv1d_k(
    const float* __restrict__ x, const float* __restrict__ w,
    const float* __restrict__ b, ushort* __restrict__ h) {
    __shared__ float sx[16 * 657 + 32];   // +32 pad: garbage reads for f>=653 stay in-bounds
    const int n = blockIdx.x;
    const int g = blockIdx.y;
    const int tid = threadIdx.x;
    const float* xg = x + ((size_t)n * 64 + g * 16) * 657;
    for (int i = tid; i < 16 * 657; i += 512) sx[i] = xg[i];
    if (tid < 32) sx[16 * 657 + tid] = 0.f;
    __syncthreads();
    const int qc = tid >> 7;              // 0..3 (wave-uniform)
    const int fl = tid & 127;
    const int o0 = g * 64 + qc * 16;
    float bv[16];
#pragma unroll
    for (int oo = 0; oo < 16; ++oo) bv[oo] = b[o0 + oo];
    const float* wq = w + o0 * 80;
    for (int f = fl; f < KP; f += 128) {
        float acc[16];
#pragma unroll
        for (int oo = 0; oo < 16; ++oo) acc[oo] = bv[oo];
#pragma unroll
        for (int i = 0; i < 16; ++i) {
            float xv[5];
#pragma unroll
            for (int k = 0; k < 5; ++k) xv[k] = sx[i * 657 + f + k];
#pragma unroll
            for (int oo = 0; oo < 16; ++oo) {
                const float* wp = wq + oo * 80 + i * 5;
                acc[oo] = fmaf(xv[0], wp[0], acc[oo]);
                acc[oo] = fmaf(xv[1], wp[1], acc[oo]);
                acc[oo] = fmaf(xv[2], wp[2], acc[oo]);
                acc[oo] = fmaf(xv[3], wp[3], acc[oo]);
                acc[oo] = fmaf(xv[4], wp[4], acc[oo]);
            }
        }
        const bool valid = f < FF;
#pragma unroll
        for (int oo = 0; oo < 16; ++oo)
            h[(size_t)(n * CCH + o0 + oo) * KP + f] = valid ? f_to_bfbits(acc[oo]) : (ushort)0;
    }
}

// ---------------------------------------------------------------------------
// Segment-max gather in bf16 domain. Per node n: agg row = max over src rows.
__global__ void seg_max_k(const ushort* __restrict__ h, ushort* __restrict__ agg,
                          const int* __restrict__ off, const int* __restrict__ lst) {
    int j = blockIdx.x * 256 + threadIdx.x;   // 0..21503 = c*84 + chunk
    int c = j / 84;
    int chunk = j % 84;
    int n = blockIdx.y;
    int o0 = off[n], o1 = off[n + 1];
    size_t dsti = ((size_t)(n * CCH + c)) * KP + chunk * 8;
    if (o0 == o1) {
        *(uint4*)(agg + dsti) = make_uint4(0, 0, 0, 0);
        return;
    }
    float m[8];
#pragma unroll
    for (int i = 0; i < 8; ++i) m[i] = -3.4e38f;
    for (int e = o0; e < o1; ++e) {
        int s = lst[e];
        const uint4 v = *(const uint4*)(h + ((size_t)(s * CCH + c)) * KP + chunk * 8);
        unsigned int u[4] = {v.x, v.y, v.z, v.w};
#pragma unroll
        for (int q = 0; q < 4; ++q) {
            float lo = __uint_as_float(u[q] << 16);
            float hi = __uint_as_float(u[q] & 0xFFFF0000u);
            m[2*q]   = fmaxf(m[2*q],   lo);
            m[2*q+1] = fmaxf(m[2*q+1], hi);
        }
    }
    unsigned int o[4];
#pragma unroll
    for (int q = 0; q < 4; ++q) {
        unsigned int a = __float_as_uint(m[2*q])   >> 16;
        unsigned int bq = __float_as_uint(m[2*q+1]) & 0xFFFF0000u;
        o[q] = a | bq;
    }
    *(uint4*)(agg + dsti) = make_uint4(o[0], o[1], o[2], o[3]);
}

// ---------------------------------------------------------------------------
// MFMA GEMM: Hnxt[m][n] = sum_k Agg[m][k]Wl[n][k] + sum_k Hcur[m][k]Wr[n][k] + b[n]
// 128x128 tile, 4 waves (2x2 of 64x64), BK=32, global_load_lds staging.
// LDS bank-conflict fix (rule 21, both-sides swizzle): linear LDS dest, the
// per-lane GLOBAL chunk is permuted by chunk^((row>>1)&3); ds_read applies the
// same involution -> 2-way max (free) instead of 8-way.
__global__ __launch_bounds__(256) void sage_gemm_k(
    const ushort* __restrict__ Agg, const ushort* __restrict__ Hcur,
    const ushort* __restrict__ Wc, const float* __restrict__ bias,
    ushort* __restrict__ Hnxt)
{
    __shared__ ushort As[128 * 32];
    __shared__ ushort Bs[128 * 32];
    const int tid  = threadIdx.x;
    const int lane = tid & 63;
    const int wid  = tid >> 6;
    const int bm = blockIdx.x * 128;
    const int bn = blockIdx.y * 128;
    const int wm = (wid >> 1) * 64;
    const int wn = (wid & 1) * 64;

    f32x4 acc[4][4];
#pragma unroll
    for (int i = 0; i < 4; ++i)
#pragma unroll
        for (int j = 0; j < 4; ++j) acc[i][j] = 0.f;

    const int srow   = lane >> 2;                    // 0..15
    const int schunk = lane & 3;                     // 0..3
    const int schk   = (schunk ^ ((srow >> 1) & 3)) * 8;  // swizzled global chunk
    ushort* lA = As + wid * 16 * 32;
    ushort* lB = Bs + wid * 16 * 32;
    const int lr  = lane & 15;
    const int cc  = lane >> 4;                       // 0..3
    const int kc  = (cc ^ ((lr >> 1) & 3)) * 8;      // swizzled read slot

    for (int pass = 0; pass < 2; ++pass) {
        const ushort* Ab = pass ? Hcur : Agg;
        const ushort* Wb = Wc + (size_t)pass * NPAD * KP;
        for (int k0 = 0; k0 < KP; k0 += 32) {
            const ushort* ga0 = Ab + (size_t)(bm + wid * 16 + srow) * KP + k0 + schk;
            const ushort* gb0 = Wb + (size_t)(bn + wid * 16 + srow) * KP + k0 + schk;
            gl_lds16(ga0, lA);
            gl_lds16(ga0 + (size_t)64 * KP, lA + 64 * 32);
            gl_lds16(gb0, lB);
            gl_lds16(gb0 + (size_t)64 * KP, lB + 64 * 32);
            __syncthreads();
            bf16x8 af[4], bfr[4];
#pragma unroll
            for (int i = 0; i < 4; ++i)
                af[i] = *(const bf16x8*)&As[(wm + i * 16 + lr) * 32 + kc];
#pragma unroll
            for (int j = 0; j < 4; ++j)
                bfr[j] = *(const bf16x8*)&Bs[(wn + j * 16 + lr) * 32 + kc];
#pragma unroll
            for (int i = 0; i < 4; ++i)
#pragma unroll
                for (int j = 0; j < 4; ++j)
                    acc[i][j] = __builtin_amdgcn_mfma_f32_16x16x32_bf16(
                        af[i], bfr[j], acc[i][j], 0, 0, 0);
            __syncthreads();
        }
    }
    const int lg = lane >> 4;
#pragma unroll
    for (int j = 0; j < 4; ++j) {
        int n = bn + wn + j * 16 + lr;
        if (n >= KP) continue;
        bool valid = n < FF;
        float bv = valid ? bias[n] : 0.f;
#pragma unroll
        for (int i = 0; i < 4; ++i) {
#pragma unroll
            for (int r = 0; r < 4; ++r) {
                int m = bm + wm + i * 16 + lg * 4 + r;
                float v = valid ? (acc[i][j][r] + bv) : 0.f;
                Hnxt[(size_t)m * KP + n] = f_to_bfbits(v);
            }
        }
    }
}

// ---------------------------------------------------------------------------
// Mean over nodes: pool[c][f] fp32, from bf16 h.
__global__ void pool_k(const ushort* __restrict__ h, float* __restrict__ pool) {
    int j = blockIdx.x * 256 + threadIdx.x;   // c*84 + chunk
    if (j >= 256 * 84) return;
    int c = j / 84;
    int chunk = j % 84;
    float s[8];
#pragma unroll
    for (int i = 0; i < 8; ++i) s[i] = 0.f;
    for (int n = 0; n < NN; ++n) {
        const uint4 v = *(const uint4*)(h + ((size_t)(n * CCH + c)) * KP + chunk * 8);
        unsigned int u[4] = {v.x, v.y, v.z, v.w};
#pragma unroll
        for (int q = 0; q < 4; ++q) {
            s[2*q]   += __uint_as_float(u[q] << 16);
            s[2*q+1] += __uint_as_float(u[q] & 0xFFFF0000u);
        }
    }
    const float inv = 1.0f / NN;
    float* dst = pool + (size_t)c * KP + chunk * 8;
#pragma unroll
    for (int i = 0; i < 8; ++i) dst[i] = s[i] * inv;
}

// ---------------------------------------------------------------------------
__device__ __forceinline__ float gelu_exact(float v) {
    return 0.5f * v * (1.0f + erff(v * 0.70710678118654752f));
}

__global__ void head_k(const float* __restrict__ pool,
                       const float* __restrict__ w1, const float* __restrict__ b1,
                       const float* __restrict__ w2, const float* __restrict__ b2,
                       const float* __restrict__ w3, const float* __restrict__ b3,
                       float* __restrict__ out) {
    __shared__ float row[FF];
    __shared__ float h1[128];
    __shared__ float h2[32];
    __shared__ float sc[4];
    const int c = blockIdx.x;
    const int t = threadIdx.x;
    for (int i = t; i < FF; i += 128) row[i] = pool[(size_t)c * KP + i];
    __syncthreads();
    {
        const float* wp = w1 + (size_t)t * FF;
        float s = b1[t];
        for (int i = 0; i < FF; ++i) s = fmaf(row[i], wp[i], s);
        h1[t] = gelu_exact(s);
    }
    __syncthreads();
    if (t < 32) {
        const float* wp = w2 + (size_t)t * 128;
        float s = b2[t];
#pragma unroll
        for (int i = 0; i < 128; ++i) s = fmaf(h1[i], wp[i], s);
        h2[t] = gelu_exact(s);
    }
    __syncthreads();
    if (t < 4) {
        const float* wp = w3 + (size_t)t * 32;
        float s = b3[t];
#pragma unroll
        for (int i = 0; i < 32; ++i) s = fmaf(h2[i], wp[i], s);
        sc[t] = s;
    }
    __syncthreads();
    if (t < 4) {
        float mx = fmaxf(fmaxf(sc[0], sc[1]), fmaxf(sc[2], sc[3]));
        float e0 = __expf(sc[0] - mx), e1 = __expf(sc[1] - mx);
        float e2 = __expf(sc[2] - mx), e3 = __expf(sc[3] - mx);
        float inv = 1.0f / (e0 + e1 + e2 + e3);
        float ev = (t == 0) ? e0 : (t == 1) ? e1 : (t == 2) ? e2 : e3;
        out[(size_t)c * 4 + t] = ev * inv;
    }
}

// ---------------------------------------------------------------------------
extern "C" void kernel_launch(void* const* d_in, const int* in_sizes, int n_in,
                              void* d_out, int out_size, void* d_ws, size_t ws_size,
                              hipStream_t stream) {
    const float* x      = (const float*)d_in[0];
    const int*   ei     = (const int*)  d_in[1];
    const float* conv_w = (const float*)d_in[2];
    const float* conv_b = (const float*)d_in[3];
    const float* wl     = (const float*)d_in[4];
    const float* wr     = (const float*)d_in[5];
    const float* sb     = (const float*)d_in[6];
    const float* fc1w   = (const float*)d_in[7];
    const float* fc1b   = (const float*)d_in[8];
    const float* fc2w   = (const float*)d_in[9];
    const float* fc2b   = (const float*)d_in[10];
    const float* fc3w   = (const float*)d_in[11];
    const float* fc3b   = (const float*)d_in[12];
    float* out = (float*)d_out;

    ushort* hA  = (ushort*)d_ws;
    ushort* hB  = hA + SZH;
    ushort* agg = hB + SZH;
    ushort* wc  = agg + SZH;
    float*  pool = (float*)(wc + (size_t)2 * NPAD * KP);
    int*    off  = (int*)(pool + (size_t)CCH * KP);
    int*    lst  = off + 128;

    build_csr_k<<<1, 256, 0, stream>>>(ei, off, lst);
    build_wc_k<<<(2 * NPAD * KP + 255) / 256, 256, 0, stream>>>(wl, wr, wc);
    {
        dim3 cgrid(NN, 4);
        conv1d_k<<<cgrid, 512, 0, stream>>>(x, conv_w, conv_b, hA);
    }

    dim3 sg_grid(84, NN);
    dim3 gm_grid(MM / 128, NPAD / 128);
    ushort* cur = hA;
    ushort* nxt = hB;
    for (int layer = 0; layer < 3; ++layer) {
        seg_max_k<<<sg_grid, 256, 0, stream>>>(cur, agg, off, lst);
        sage_gemm_k<<<gm_grid, 256, 0, stream>>>(agg, cur, wc, sb, nxt);
        ushort* tmp = cur; cur = nxt; nxt = tmp;
    }
    pool_k<<<84, 256, 0, stream>>>(cur, pool);
    head_k<<<CCH, 128, 0, stream>>>(pool, fc1w, fc1b, fc2w, fc2b, fc3w, fc3b, out);
}

// Round 5
// 641.821 us; speedup vs baseline: 4.0452x; 4.0452x over previous
//
#include <hip/hip_runtime.h>
#include <hip/hip_bf16.h>
#include <math.h>

// Problem constants
#define NN 116           // nodes
#define NE 1160          // edges
#define CCH 256          // channels after conv
#define FF 653           // feature dim
#define KP 672           // padded feature stride (bf16), mult of 32
#define MM (NN*CCH)      // 29696 GEMM rows (= 232 * 128)
#define NPAD 768         // padded N for weight matrix (6 * 128)
#define SZH ((size_t)MM*KP)   // elems per bf16 h buffer

typedef unsigned short ushort;
typedef short bf16x8 __attribute__((ext_vector_type(8)));
typedef float f32x4 __attribute__((ext_vector_type(4)));

// ---- bf16 helpers (bit-level) ----------------------------------------------
__device__ __forceinline__ float bfbits_to_f(ushort u) {
    unsigned int w = ((unsigned int)u) << 16;
    return __uint_as_float(w);
}
__device__ __forceinline__ ushort f_to_bfbits(float f) {   // RTNE
    unsigned int u = __float_as_uint(f);
    u += 0x7FFFu + ((u >> 16) & 1u);
    return (ushort)(u >> 16);
}

__device__ __forceinline__ void gl_lds16(const void* g, void* l) {
    __builtin_amdgcn_global_load_lds(
        (const __attribute__((address_space(1))) unsigned int*)g,
        (__attribute__((address_space(3))) unsigned int*)l, 16, 0, 0);
}

// ---------------------------------------------------------------------------
// CSR build: per-dst incoming-edge source lists.
__global__ void build_csr_k(const int* __restrict__ ei, int* __restrict__ off,
                            int* __restrict__ lst) {
    __shared__ int s_cnt[NN];
    __shared__ int s_off[NN + 1];
    int t = threadIdx.x;
    for (int i = t; i < NN; i += blockDim.x) s_cnt[i] = 0;
    __syncthreads();
    for (int e = t; e < NE; e += blockDim.x) atomicAdd(&s_cnt[ei[NE + e]], 1);
    __syncthreads();
    if (t == 0) {
        s_off[0] = 0;
        for (int i = 0; i < NN; ++i) s_off[i + 1] = s_off[i] + s_cnt[i];
    }
    __syncthreads();
    for (int i = t; i < NN; i += blockDim.x) { off[i] = s_off[i]; s_cnt[i] = 0; }
    if (t == 0) off[NN] = s_off[NN];
    __syncthreads();
    for (int e = t; e < NE; e += blockDim.x) {
        int d = ei[NE + e];
        int p = atomicAdd(&s_cnt[d], 1);
        lst[s_off[d] + p] = ei[e];
    }
}

// ---------------------------------------------------------------------------
// Quantize + concat weights: Wc[2][NPAD][KP] bf16; pass0=Wl, pass1=Wr, zero pad.
__global__ void build_wc_k(const float* __restrict__ wl, const float* __restrict__ wr,
                           ushort* __restrict__ wc) {
    int idx = blockIdx.x * 256 + threadIdx.x;
    const int total = 2 * NPAD * KP;
    if (idx >= total) return;
    int k = idx % KP;
    int rem = idx / KP;
    int n = rem % NPAD;
    int p = rem / NPAD;
    float v = 0.f;
    if (n < FF && k < FF) v = (p ? wr : wl)[(size_t)n * FF + k];
    wc[idx] = f_to_bfbits(v);
}

// ---------------------------------------------------------------------------
// Grouped Conv1d -> bf16 h [MM][KP], zero pads.
// Thread = f-position; blockIdx.z = 16-out-channel chunk (UNIFORM -> weights
// and bias ride the scalar (s_load) pipe — critical, see R4 post-mortem).
// i-outer / oo-inner: xv[5] window + acc[16] keeps live VGPRs ~30 so x loads
// (80/thread, reused 16x) stay hoisted out of the FMA loop.
__global__ __launch_bounds__(256) void conv1d_k(
    const float* __restrict__ x, const float* __restrict__ w,
    const float* __restrict__ b, ushort* __restrict__ h) {
    const int f  = blockIdx.x * 256 + threadIdx.x;   // 0..767
    if (f >= KP) return;
    const int n  = blockIdx.y;
    const int o0 = blockIdx.z * 16;   // uniform out-channel chunk
    const int g  = o0 >> 6;           // group
    if (f >= FF) {                    // zero-pad band f in [653, 672)
#pragma unroll
        for (int oo = 0; oo < 16; ++oo)
            h[(size_t)(n * CCH + o0 + oo) * KP + f] = 0;
        return;
    }
    const float* xp = x + ((size_t)n * 64 + g * 16) * 657 + f;
    const float* wq = w + o0 * 80;    // uniform
    float acc[16];
#pragma unroll
    for (int oo = 0; oo < 16; ++oo) acc[oo] = b[o0 + oo];
#pragma unroll
    for (int i = 0; i < 16; ++i) {
        float xv[5];
#pragma unroll
        for (int k = 0; k < 5; ++k) xv[k] = xp[i * 657 + k];
#pragma unroll
        for (int oo = 0; oo < 16; ++oo) {
            const float* wp = wq + oo * 80 + i * 5;   // uniform -> s_load
            acc[oo] = fmaf(xv[0], wp[0], acc[oo]);
            acc[oo] = fmaf(xv[1], wp[1], acc[oo]);
            acc[oo] = fmaf(xv[2], wp[2], acc[oo]);
            acc[oo] = fmaf(xv[3], wp[3], acc[oo]);
            acc[oo] = fmaf(xv[4], wp[4], acc[oo]);
        }
    }
#pragma unroll
    for (int oo = 0; oo < 16; ++oo)
        h[(size_t)(n * CCH + o0 + oo) * KP + f] = f_to_bfbits(acc[oo]);
}

// ---------------------------------------------------------------------------
// Segment-max gather in bf16 domain. Per node n: agg row = max over src rows.
__global__ void seg_max_k(const ushort* __restrict__ h, ushort* __restrict__ agg,
                          const int* __restrict__ off, const int* __restrict__ lst) {
    int j = blockIdx.x * 256 + threadIdx.x;   // 0..21503 = c*84 + chunk
    int c = j / 84;
    int chunk = j % 84;
    int n = blockIdx.y;
    int o0 = off[n], o1 = off[n + 1];
    size_t dsti = ((size_t)(n * CCH + c)) * KP + chunk * 8;
    if (o0 == o1) {
        *(uint4*)(agg + dsti) = make_uint4(0, 0, 0, 0);
        return;
    }
    float m[8];
#pragma unroll
    for (int i = 0; i < 8; ++i) m[i] = -3.4e38f;
    for (int e = o0; e < o1; ++e) {
        int s = lst[e];
        const uint4 v = *(const uint4*)(h + ((size_t)(s * CCH + c)) * KP + chunk * 8);
        unsigned int u[4] = {v.x, v.y, v.z, v.w};
#pragma unroll
        for (int q = 0; q < 4; ++q) {
            float lo = __uint_as_float(u[q] << 16);
            float hi = __uint_as_float(u[q] & 0xFFFF0000u);
            m[2*q]   = fmaxf(m[2*q],   lo);
            m[2*q+1] = fmaxf(m[2*q+1], hi);
        }
    }
    unsigned int o[4];
#pragma unroll
    for (int q = 0; q < 4; ++q) {
        unsigned int a = __float_as_uint(m[2*q])   >> 16;
        unsigned int bq = __float_as_uint(m[2*q+1]) & 0xFFFF0000u;
        o[q] = a | bq;
    }
    *(uint4*)(agg + dsti) = make_uint4(o[0], o[1], o[2], o[3]);
}

// ---------------------------------------------------------------------------
// MFMA GEMM: Hnxt[m][n] = sum_k Agg[m][k]Wl[n][k] + sum_k Hcur[m][k]Wr[n][k] + b[n]
// 128x128 tile, 4 waves (2x2 of 64x64), BK=32, global_load_lds staging.
// Both-sides LDS swizzle (rule 21): linear LDS dest, per-lane GLOBAL chunk
// permuted by chunk^((row>>1)&3); ds_read applies the same involution.
__global__ __launch_bounds__(256) void sage_gemm_k(
    const ushort* __restrict__ Agg, const ushort* __restrict__ Hcur,
    const ushort* __restrict__ Wc, const float* __restrict__ bias,
    ushort* __restrict__ Hnxt)
{
    __shared__ ushort As[128 * 32];
    __shared__ ushort Bs[128 * 32];
    const int tid  = threadIdx.x;
    const int lane = tid & 63;
    const int wid  = tid >> 6;
    const int bm = blockIdx.x * 128;
    const int bn = blockIdx.y * 128;
    const int wm = (wid >> 1) * 64;
    const int wn = (wid & 1) * 64;

    f32x4 acc[4][4];
#pragma unroll
    for (int i = 0; i < 4; ++i)
#pragma unroll
        for (int j = 0; j < 4; ++j) acc[i][j] = 0.f;

    const int srow   = lane >> 2;                    // 0..15
    const int schunk = lane & 3;                     // 0..3
    const int schk   = (schunk ^ ((srow >> 1) & 3)) * 8;  // swizzled global chunk
    ushort* lA = As + wid * 16 * 32;
    ushort* lB = Bs + wid * 16 * 32;
    const int lr  = lane & 15;
    const int cc  = lane >> 4;                       // 0..3
    const int kc  = (cc ^ ((lr >> 1) & 3)) * 8;      // swizzled read slot

    for (int pass = 0; pass < 2; ++pass) {
        const ushort* Ab = pass ? Hcur : Agg;
        const ushort* Wb = Wc + (size_t)pass * NPAD * KP;
        for (int k0 = 0; k0 < KP; k0 += 32) {
            const ushort* ga0 = Ab + (size_t)(bm + wid * 16 + srow) * KP + k0 + schk;
            const ushort* gb0 = Wb + (size_t)(bn + wid * 16 + srow) * KP + k0 + schk;
            gl_lds16(ga0, lA);
            gl_lds16(ga0 + (size_t)64 * KP, lA + 64 * 32);
            gl_lds16(gb0, lB);
            gl_lds16(gb0 + (size_t)64 * KP, lB + 64 * 32);
            __syncthreads();
            bf16x8 af[4], bfr[4];
#pragma unroll
            for (int i = 0; i < 4; ++i)
                af[i] = *(const bf16x8*)&As[(wm + i * 16 + lr) * 32 + kc];
#pragma unroll
            for (int j = 0; j < 4; ++j)
                bfr[j] = *(const bf16x8*)&Bs[(wn + j * 16 + lr) * 32 + kc];
#pragma unroll
            for (int i = 0; i < 4; ++i)
#pragma unroll
                for (int j = 0; j < 4; ++j)
                    acc[i][j] = __builtin_amdgcn_mfma_f32_16x16x32_bf16(
                        af[i], bfr[j], acc[i][j], 0, 0, 0);
            __syncthreads();
        }
    }
    const int lg = lane >> 4;
#pragma unroll
    for (int j = 0; j < 4; ++j) {
        int n = bn + wn + j * 16 + lr;
        if (n >= KP) continue;
        bool valid = n < FF;
        float bv = valid ? bias[n] : 0.f;
#pragma unroll
        for (int i = 0; i < 4; ++i) {
#pragma unroll
            for (int r = 0; r < 4; ++r) {
                int m = bm + wm + i * 16 + lg * 4 + r;
                float v = valid ? (acc[i][j][r] + bv) : 0.f;
                Hnxt[(size_t)m * KP + n] = f_to_bfbits(v);
            }
        }
    }
}

// ---------------------------------------------------------------------------
// Mean over nodes: pool[c][f] fp32, from bf16 h.
__global__ void pool_k(const ushort* __restrict__ h, float* __restrict__ pool) {
    int j = blockIdx.x * 256 + threadIdx.x;   // c*84 + chunk
    if (j >= 256 * 84) return;
    int c = j / 84;
    int chunk = j % 84;
    float s[8];
#pragma unroll
    for (int i = 0; i < 8; ++i) s[i] = 0.f;
    for (int n = 0; n < NN; ++n) {
        const uint4 v = *(const uint4*)(h + ((size_t)(n * CCH + c)) * KP + chunk * 8);
        unsigned int u[4] = {v.x, v.y, v.z, v.w};
#pragma unroll
        for (int q = 0; q < 4; ++q) {
            s[2*q]   += __uint_as_float(u[q] << 16);
            s[2*q+1] += __uint_as_float(u[q] & 0xFFFF0000u);
        }
    }
    const float inv = 1.0f / NN;
    float* dst = pool + (size_t)c * KP + chunk * 8;
#pragma unroll
    for (int i = 0; i < 8; ++i) dst[i] = s[i] * inv;
}

// ---------------------------------------------------------------------------
__device__ __forceinline__ float gelu_exact(float v) {
    return 0.5f * v * (1.0f + erff(v * 0.70710678118654752f));
}

__global__ void head_k(const float* __restrict__ pool,
                       const float* __restrict__ w1, const float* __restrict__ b1,
                       const float* __restrict__ w2, const float* __restrict__ b2,
                       const float* __restrict__ w3, const float* __restrict__ b3,
                       float* __restrict__ out) {
    __shared__ float row[FF];
    __shared__ float h1[128];
    __shared__ float h2[32];
    __shared__ float sc[4];
    const int c = blockIdx.x;
    const int t = threadIdx.x;
    for (int i = t; i < FF; i += 128) row[i] = pool[(size_t)c * KP + i];
    __syncthreads();
    {
        const float* wp = w1 + (size_t)t * FF;
        float s = b1[t];
        for (int i = 0; i < FF; ++i) s = fmaf(row[i], wp[i], s);
        h1[t] = gelu_exact(s);
    }
    __syncthreads();
    if (t < 32) {
        const float* wp = w2 + (size_t)t * 128;
        float s = b2[t];
#pragma unroll
        for (int i = 0; i < 128; ++i) s = fmaf(h1[i], wp[i], s);
        h2[t] = gelu_exact(s);
    }
    __syncthreads();
    if (t < 4) {
        const float* wp = w3 + (size_t)t * 32;
        float s = b3[t];
#pragma unroll
        for (int i = 0; i < 32; ++i) s = fmaf(h2[i], wp[i], s);
        sc[t] = s;
    }
    __syncthreads();
    if (t < 4) {
        float mx = fmaxf(fmaxf(sc[0], sc[1]), fmaxf(sc[2], sc[3]));
        float e0 = __expf(sc[0] - mx), e1 = __expf(sc[1] - mx);
        float e2 = __expf(sc[2] - mx), e3 = __expf(sc[3] - mx);
        float inv = 1.0f / (e0 + e1 + e2 + e3);
        float ev = (t == 0) ? e0 : (t == 1) ? e1 : (t == 2) ? e2 : e3;
        out[(size_t)c * 4 + t] = ev * inv;
    }
}

// ---------------------------------------------------------------------------
extern "C" void kernel_launch(void* const* d_in, const int* in_sizes, int n_in,
                              void* d_out, int out_size, void* d_ws, size_t ws_size,
                              hipStream_t stream) {
    const float* x      = (const float*)d_in[0];
    const int*   ei     = (const int*)  d_in[1];
    const float* conv_w = (const float*)d_in[2];
    const float* conv_b = (const float*)d_in[3];
    const float* wl     = (const float*)d_in[4];
    const float* wr     = (const float*)d_in[5];
    const float* sb     = (const float*)d_in[6];
    const float* fc1w   = (const float*)d_in[7];
    const float* fc1b   = (const float*)d_in[8];
    const float* fc2w   = (const float*)d_in[9];
    const float* fc2b   = (const float*)d_in[10];
    const float* fc3w   = (const float*)d_in[11];
    const float* fc3b   = (const float*)d_in[12];
    float* out = (float*)d_out;

    ushort* hA  = (ushort*)d_ws;
    ushort* hB  = hA + SZH;
    ushort* agg = hB + SZH;
    ushort* wc  = agg + SZH;
    float*  pool = (float*)(wc + (size_t)2 * NPAD * KP);
    int*    off  = (int*)(pool + (size_t)CCH * KP);
    int*    lst  = off + 128;

    build_csr_k<<<1, 256, 0, stream>>>(ei, off, lst);
    build_wc_k<<<(2 * NPAD * KP + 255) / 256, 256, 0, stream>>>(wl, wr, wc);
    {
        dim3 cgrid(3, NN, 16);
        conv1d_k<<<cgrid, 256, 0, stream>>>(x, conv_w, conv_b, hA);
    }

    dim3 sg_grid(84, NN);
    dim3 gm_grid(MM / 128, NPAD / 128);
    ushort* cur = hA;
    ushort* nxt = hB;
    for (int layer = 0; layer < 3; ++layer) {
        seg_max_k<<<sg_grid, 256, 0, stream>>>(cur, agg, off, lst);
        sage_gemm_k<<<gm_grid, 256, 0, stream>>>(agg, cur, wc, sb, nxt);
        ushort* tmp = cur; cur = nxt; nxt = tmp;
    }
    pool_k<<<84, 256, 0, stream>>>(cur, pool);
    head_k<<<CCH, 128, 0, stream>>>(pool, fc1w, fc1b, fc2w, fc2b, fc3w, fc3b, out);
}